// Round 11
// baseline (153.273 us; speedup 1.0000x reference)
//
#include <hip/hip_runtime.h>
#include <hip/hip_bf16.h>
#include <math.h>

#define B_  32
#define C_  256
#define HW_ 4096
#define K_  5
#define P_  64           // positions per tile
#define NT_ 64           // HW_/P_
#define PS_ 36           // padded LDS row stride (u32 words), 144B rows: 16B aligned

typedef __hip_bfloat16 bf16;
typedef unsigned int u32;
typedef __attribute__((ext_vector_type(8))) short bf16x8;
typedef __attribute__((ext_vector_type(4))) float f32x4;

// ---------- dtype-flexible load/store ----------
template<bool BF>
__device__ inline float LD(const void* p, size_t i) {
    if (BF) return __bfloat162float(((const bf16*)p)[i]);
    return ((const float*)p)[i];
}
template<bool BF>
__device__ inline void ST(void* p, size_t i, float v) {
    if (BF) ((bf16*)p)[i] = __float2bfloat16(v);
    else    ((float*)p)[i] = v;
}
template<bool BF>
__device__ inline float4 LD4(const void* p, size_t i) {
    if (BF) {
        ushort4 u = *(const ushort4*)((const unsigned short*)p + i);
        float4 r;
        r.x = __uint_as_float(((u32)u.x) << 16);
        r.y = __uint_as_float(((u32)u.y) << 16);
        r.z = __uint_as_float(((u32)u.z) << 16);
        r.w = __uint_as_float(((u32)u.w) << 16);
        return r;
    }
    return *(const float4*)((const float*)p + i);
}
__device__ inline u32 packbf2(float a, float b) {   // a -> low 16
    bf16 x = __float2bfloat16(a), y = __float2bfloat16(b);
    return (((u32)*(unsigned short*)&y) << 16) | (u32)(*(unsigned short*)&x);
}
__device__ inline float lo16f(u32 u) { return __uint_as_float(u << 16); }
__device__ inline float hi16f(u32 u) { return __uint_as_float(u & 0xffff0000u); }

// ---------- in-kernel dtype detect (wave-reduced, 1 atomic per wave) ----------
__device__ int detect_bf(const void* feat, int* cntL) {
    int t = threadIdx.x;
    if (t == 0) *cntL = 0;
    __syncthreads();
    const unsigned short* u = (const unsigned short*)feat;
    int local = 0;
    for (int i = t; i < 4096; i += blockDim.x) {
        float v = __uint_as_float(((u32)u[i]) << 16);
        float a = fabsf(v);
        local += (a >= 1e-4f && a <= 100.f) ? 1 : 0;
    }
    for (int o = 32; o > 0; o >>= 1) local += __shfl_down(local, o, 64);
    if ((t & 63) == 0) atomicAdd(cntL, local);
    __syncthreads();
    return (*cntL > 3072) ? 1 : 0;
}

// ---------- block reductions (256 threads) ----------
__device__ inline float blk_sum(float v, float* sh) {
    for (int o = 32; o > 0; o >>= 1) v += __shfl_down(v, o, 64);
    int w = threadIdx.x >> 6;
    __syncthreads();
    if ((threadIdx.x & 63) == 0) sh[w] = v;
    __syncthreads();
    return sh[0] + sh[1] + sh[2] + sh[3];
}

// ================= 1: FUSED sim + softmax partial + pt partial (MFMA) ==========
// 512 thr (8 waves x 32ch), tile = 64 positions. Per wave: 16 lanes x 4 pos,
// 4 channel-quarters. 2-round finalize. Phase 2: 16x16x32 MFMA over positions.
template<bool BF>
__device__ void simpt_body(const void* feat, const void* mask, const void* temp,
                           const void* pq, float* ptp, float* mz, float* smem) {
    u32*   featB = (u32*)smem;                 // [256][PS_] = 9216 u32 (36,864 B)
    float* red   = smem + 9216;                // 1536 f32 ([2][6][128] rounds)
    u32*   wB    = (u32*)red;                  // alias: [16][PS_], rows 0..4 valid
    float* qL    = smem + 9216 + 1536;         // 1280 f32
    float* simL  = qL;                         // alias after phase 1 (320 used)
    float* sc    = qL + 1280;                  // scalars
    int t = threadIdx.x, lane = t & 63, q = t >> 6;
    int b = blockIdx.y, tile = blockIdx.x;

    // qnorm: waves 0..4 each normalize one query row
    if (q < K_) {
        float4 v = LD4<BF>(pq, (size_t)q * C_ + lane * 4);
        float ss = v.x * v.x + v.y * v.y + v.z * v.z + v.w * v.w;
        for (int o = 32; o > 0; o >>= 1) ss += __shfl_xor(ss, o, 64);
        float inv = 1.0f / fmaxf(sqrtf(ss), 1e-12f);
        *(float4*)(qL + q * C_ + lane * 4) =
            make_float4(v.x * inv, v.y * inv, v.z * inv, v.w * inv);
    }
    if (t == 0) sc[0] = 1.0f / fmaxf(LD<BF>(temp, 0), 0.01f);
    __syncthreads();

    // ---- phase 1: 8 iters, c = c0 + 4j + quarter; 16 lanes x 4 pos ----
    int c0 = q * 32, qr = lane >> 4, lm = lane & 15;
    float sa[4] = {0.f, 0.f, 0.f, 0.f};
    float da[K_][4];
    #pragma unroll
    for (int k = 0; k < K_; k++)
        #pragma unroll
        for (int i = 0; i < 4; i++) da[k][i] = 0.f;
    size_t gbase = (size_t)b * C_ * HW_ + (size_t)tile * P_ + lm * 4;
    #pragma unroll 4
    for (int j = 0; j < 8; j++) {
        int c = c0 + 4 * j + qr;
        float4 f = LD4<BF>(feat, gbase + (size_t)c * HW_);
        sa[0] += f.x * f.x; sa[1] += f.y * f.y; sa[2] += f.z * f.z; sa[3] += f.w * f.w;
        #pragma unroll
        for (int k = 0; k < K_; k++) {
            float qv = qL[k * C_ + c];
            da[k][0] += f.x * qv; da[k][1] += f.y * qv;
            da[k][2] += f.z * qv; da[k][3] += f.w * qv;
        }
        *(uint2*)&featB[c * PS_ + 2 * lm] =
            make_uint2(packbf2(f.x, f.y), packbf2(f.z, f.w));
    }
    // combine 4 channel-quarters -> lanes 0..15
    #pragma unroll
    for (int i = 0; i < 4; i++) {
        sa[i] += __shfl_down(sa[i], 32, 64);
        sa[i] += __shfl_down(sa[i], 16, 64);
    }
    #pragma unroll
    for (int k = 0; k < K_; k++)
        #pragma unroll
        for (int i = 0; i < 4; i++) {
            da[k][i] += __shfl_down(da[k][i], 32, 64);
            da[k][i] += __shfl_down(da[k][i], 16, 64);
        }

    // ---- finalize: 2 rounds x 2 positions; pos = 4*lm + 2r + ii ----
    float tinv = sc[0];
    for (int r = 0; r < 2; r++) {
        if (lane < 16) {
            #pragma unroll
            for (int ii = 0; ii < 2; ii++) {
                int i = 2 * r + ii;
                red[(ii * 6 + 0) * 128 + q * 16 + lane] = sa[i];
                #pragma unroll
                for (int k = 0; k < K_; k++)
                    red[(ii * 6 + 1 + k) * 128 + q * 16 + lane] = da[k][i];
            }
        }
        __syncthreads();
        if (t < 160) {
            int kk = t >> 5, rem = t & 31, ii = rem >> 4, m = rem & 15;
            int n = 4 * m + 2 * r + ii;
            float ssum = 0.f, dsum = 0.f;
            #pragma unroll
            for (int g = 0; g < 8; g++) {
                ssum += red[(ii * 6 + 0) * 128 + g * 16 + m];
                dsum += red[(ii * 6 + 1 + kk) * 128 + g * 16 + m];
            }
            float mval = LD<BF>(mask, (size_t)b * HW_ + tile * P_ + n);
            simL[kk * P_ + n] = (mval > 0.f)
                ? dsum * (tinv / fmaxf(sqrtf(ssum), 1e-12f)) : -INFINITY;
        }
        __syncthreads();
    }

    // ---- wave softmax partial per k -> bf16 wB (red dead, aliased) ----
    if (q < K_) {
        float s = simL[q * P_ + lane];   // one position per lane (64 = P_)
        float m = s;
        for (int o = 32; o > 0; o >>= 1) m = fmaxf(m, __shfl_xor(m, o, 64));
        float e = (s == -INFINITY) ? 0.f : __expf(s - m);
        float z = e;
        for (int o = 32; o > 0; o >>= 1) z += __shfl_xor(z, o, 64);
        float e1 = __shfl_down(e, 1, 64);
        if ((lane & 1) == 0) wB[q * PS_ + (lane >> 1)] = packbf2(e, e1);
        if (lane == 0) {
            size_t mzb = ((size_t)(b * NT_ + tile) * K_ + q) * 2;
            mz[mzb] = m; mz[mzb + 1] = z;
        }
    }
    __syncthreads();

    // ---- phase 2: MFMA. D[row=channel][col=query-k], K=32 pos x 2 ----
    int r16 = lane & 15, g = lane >> 4;
    size_t pb = (size_t)(b * NT_ + tile) * (K_ * C_);
    #pragma unroll
    for (int sub = 0; sub < 2; sub++) {
        int ctile = q * 32 + sub * 16;
        f32x4 acc = {0.f, 0.f, 0.f, 0.f};
        #pragma unroll
        for (int s = 0; s < 2; s++) {
            bf16x8 a = *(const bf16x8*)(featB + (ctile + r16) * PS_ + 16 * s + 4 * g);
            bf16x8 bb = *(const bf16x8*)(wB + r16 * PS_ + 16 * s + 4 * g);
            acc = __builtin_amdgcn_mfma_f32_16x16x32_bf16(a, bb, acc, 0, 0, 0);
        }
        if (r16 < K_) {
            #pragma unroll
            for (int r = 0; r < 4; r++)
                ptp[pb + (size_t)r16 * C_ + ctile + 4 * g + r] = acc[r];
        }
    }
}
__global__ __launch_bounds__(512, 6) void k_simpt(const void* feat, const void* mask,
                                                  const void* temp, const void* pq,
                                                  float* ptp, float* mz) {
    __shared__ __attribute__((aligned(16))) float smem[12040];   // 48,160 B
    __shared__ int cnt;
    int flg = detect_bf(feat, &cnt);
    if (flg) simpt_body<true >(feat, mask, temp, pq, ptp, mz, smem);
    else     simpt_body<false>(feat, mask, temp, pq, ptp, mz, smem);
}

// ================= 2: merge + prep + div in one kernel =================
__device__ inline float merge_one(const float* ptp, const float* mz,
                                  int b, int kk, int c) {
    float M = -INFINITY;
    #pragma unroll 8
    for (int tl = 0; tl < NT_; tl++)
        M = fmaxf(M, mz[((size_t)(b * NT_ + tl) * K_ + kk) * 2]);
    float Zs = 0.f, acc = 0.f;
    #pragma unroll 8
    for (int tl = 0; tl < NT_; tl++) {
        size_t mzb = ((size_t)(b * NT_ + tl) * K_ + kk) * 2;
        float m_t = mz[mzb], z_t = mz[mzb + 1];
        float s = (m_t == -INFINITY) ? 0.f : __expf(m_t - M);
        Zs += z_t * s;
        acc += ptp[(size_t)(b * NT_ + tl) * (K_ * C_) + kk * C_ + c] * s;
    }
    return (Zs > 0.f) ? acc / Zs : 0.f;
}
template<bool BF>
__device__ void prep_part(const void* qw, const void* kw, const void* kb,
                          const void* vw, const void* vb, const void* ow,
                          const void* bnw, const void* bnb, const void* bnm,
                          const void* bnv, float ptv, int bk,
                          float* W2, float* b2, float* OV, float* pt, float* smem) {
    float* ptL = smem;
    float* KtL = smem + 256;
    float* VtL = smem + 512;
    float* sh  = smem + 768;
    int t = threadIdx.x;
    ptL[t] = ptv;
    pt[(size_t)bk * C_ + t] = ptv;
    __syncthreads();
    float kt = LD<BF>(kb, t), vt = LD<BF>(vb, t);
    for (int c = 0; c < C_; c += 4) {
        float4 p4 = *(float4*)(ptL + c);
        float4 kw4 = LD4<BF>(kw, (size_t)t * C_ + c);
        float4 vw4 = LD4<BF>(vw, (size_t)t * C_ + c);
        kt += kw4.x * p4.x + kw4.y * p4.y + kw4.z * p4.z + kw4.w * p4.w;
        vt += vw4.x * p4.x + vw4.y * p4.y + vw4.z * p4.z + vw4.w * p4.w;
    }
    float scale = LD<BF>(bnw, t) * rsqrtf(LD<BF>(bnv, t) + 1e-5f);
    float shift = LD<BF>(bnb, t) - LD<BF>(bnm, t) * scale;
    KtL[t] = kt * scale;
    VtL[t] = vt;
    float bpart = kt * shift;
    __syncthreads();
    float ov = 0;
    for (int c = 0; c < C_; c += 4) {
        float4 v4 = *(float4*)(VtL + c);
        float4 ow4 = LD4<BF>(ow, (size_t)t * C_ + c);
        ov += ow4.x * v4.x + ow4.y * v4.y + ow4.z * v4.z + ow4.w * v4.w;
    }
    OV[(size_t)bk * C_ + t] = ov;
    float w2 = 0;
    for (int o = 0; o < C_; o++) w2 += KtL[o] * LD<BF>(qw, (size_t)o * C_ + t);
    W2[(size_t)bk * C_ + t] = w2 * (1.0f / 16.0f);
    float bs = blk_sum(bpart, sh);
    if (t == 0) b2[bk] = bs * (1.0f / 16.0f);
}
template<bool BF>
__device__ void div_part(const float* ptp, const float* mz, const void* margin,
                         float* divpart, float* smem) {
    float* ptL = smem;
    float* rn  = smem + K_ * C_;
    float* sh  = rn + 8;
    int b = blockIdx.x - B_ * K_, t = threadIdx.x;
    for (int kk = 0; kk < K_; kk++) ptL[kk * C_ + t] = merge_one(ptp, mz, b, kk, t);
    __syncthreads();
    for (int k = 0; k < K_; k++) {
        float v = ptL[k * C_ + t];
        float s = blk_sum(v * v, sh);
        if (t == 0) rn[k] = 1.0f / fmaxf(sqrtf(s), 1e-12f);
    }
    __syncthreads();
    float m = LD<BF>(margin, 0);
    m = fminf(fmaxf(m, 0.f), 0.5f);
    int p = t >> 3, g = t & 7;
    float contrib = 0.f;
    if (p < K_ * K_) {
        int k = p / K_, j = p % K_;
        float d = 0;
        for (int c = g; c < C_; c += 8) d += ptL[k * C_ + c] * ptL[j * C_ + c];
        d += __shfl_down(d, 4, 8);
        d += __shfl_down(d, 2, 8);
        d += __shfl_down(d, 1, 8);
        if (g == 0 && k != j) contrib = fmaxf(d * rn[k] * rn[j] - m, 0.f);
    }
    float s = blk_sum(contrib, sh);
    if (t == 0) divpart[b] = s;
}
template<bool BF>
__device__ void mergeprep_body(const void* qw, const void* kw, const void* kb,
                               const void* vw, const void* vb, const void* ow,
                               const void* bnw, const void* bnb, const void* bnm,
                               const void* bnv, const void* margin,
                               const float* ptp, const float* mz,
                               float* W2, float* b2, float* OV, float* pt,
                               float* divpart, float* smem) {
    int bid = blockIdx.x, t = threadIdx.x;
    if (bid < B_ * K_) {
        int b = bid / K_, kk = bid % K_;
        float ptv = merge_one(ptp, mz, b, kk, t);
        prep_part<BF>(qw, kw, kb, vw, vb, ow, bnw, bnb, bnm, bnv,
                      ptv, bid, W2, b2, OV, pt, smem);
    } else {
        div_part<BF>(ptp, mz, margin, divpart, smem);
    }
}
__global__ void k_mergeprep(const void* feat, const void* qw, const void* kw,
                            const void* kb, const void* vw, const void* vb,
                            const void* ow, const void* bnw, const void* bnb,
                            const void* bnm, const void* bnv, const void* margin,
                            const float* ptp, const float* mz,
                            float* W2, float* b2, float* OV, float* pt, float* divpart) {
    __shared__ __attribute__((aligned(16))) float smem[K_ * C_ + 16];
    __shared__ int cnt;
    int flg = detect_bf(feat, &cnt);
    if (flg) mergeprep_body<true >(qw, kw, kb, vw, vb, ow, bnw, bnb, bnm, bnv, margin,
                                   ptp, mz, W2, b2, OV, pt, divpart, smem);
    else     mergeprep_body<false>(qw, kw, kb, vw, vb, ow, bnw, bnb, bnm, bnv, margin,
                                   ptp, mz, W2, b2, OV, pt, divpart, smem);
}

// ================= 3: fused refine-attn + residual (output via MFMA) ==========
template<bool BF>
__device__ void fin_body(const void* feat, const void* outb, const void* gamma,
                         const float* W2, const float* b2, const float* OV,
                         const float* pt, const float* divpart,
                         void* dout, float* smem) {
    u32*   featU = (u32*)smem;                  // [256][PS_] = 9216 u32
    u32*   OVp8  = featU + 256 * PS_;           // 1024 u32
    u32*   eT8   = OVp8 + 1024;                 // 256 u32 (64 pos x 4)
    u32*   zb    = eT8 + 256;                   // 4 u32 (zero block)
    float* pool  = (float*)(zb + 4);            // 1280 f32: W2p (ph1) / red (finalize)
    u32*   W2p   = (u32*)pool;                  // 640 u32
    float* red   = pool;                        // [2][5][128] = 1280 f32
    float* b2L   = pool + 1280;                 // 8
    int t = threadIdx.x, lane = t & 63, q = t >> 6;
    int b = blockIdx.y, tile = blockIdx.x;

    float g0 = LD<BF>(gamma, 0);
    for (int i = t; i < 640; i += 512) {
        W2p[i] = packbf2(W2[(size_t)b * 1280 + 2 * i], W2[(size_t)b * 1280 + 2 * i + 1]);
    }
    if (t < 256) {   // OVp8 row c=t: {g*OV[k][c]}k<5, g*ob[c], 0, 0
        float o0 = OV[(size_t)b * 1280 + 0 * C_ + t] * g0;
        float o1 = OV[(size_t)b * 1280 + 1 * C_ + t] * g0;
        float o2 = OV[(size_t)b * 1280 + 2 * C_ + t] * g0;
        float o3 = OV[(size_t)b * 1280 + 3 * C_ + t] * g0;
        float o4 = OV[(size_t)b * 1280 + 4 * C_ + t] * g0;
        float obv = LD<BF>(outb, t) * g0;
        OVp8[t * 4 + 0] = packbf2(o0, o1);
        OVp8[t * 4 + 1] = packbf2(o2, o3);
        OVp8[t * 4 + 2] = packbf2(o4, obv);
        OVp8[t * 4 + 3] = 0u;
    }
    if (t < 4) zb[t] = 0u;
    if (t < K_) b2L[t] = b2[b * K_ + t];
    __syncthreads();

    // ---- phase 1: logit partial dots + plain staging ----
    int c0 = q * 32, qr = lane >> 4, lm = lane & 15;
    size_t gbase = (size_t)b * C_ * HW_ + (size_t)tile * P_ + lm * 4;
    float la[K_][4];
    #pragma unroll
    for (int k = 0; k < K_; k++)
        #pragma unroll
        for (int i = 0; i < 4; i++) la[k][i] = 0.f;
    #pragma unroll 4
    for (int j = 0; j < 8; j++) {
        int c = c0 + 4 * j + qr;
        float4 f = LD4<BF>(feat, gbase + (size_t)c * HW_);
        #pragma unroll
        for (int k = 0; k < K_; k++) {
            u32 u = W2p[k * 128 + (c >> 1)];
            float wv = (c & 1) ? hi16f(u) : lo16f(u);
            la[k][0] += f.x * wv; la[k][1] += f.y * wv;
            la[k][2] += f.z * wv; la[k][3] += f.w * wv;
        }
        *(uint2*)&featU[c * PS_ + 2 * lm] =
            make_uint2(packbf2(f.x, f.y), packbf2(f.z, f.w));
    }
    #pragma unroll
    for (int k = 0; k < K_; k++)
        #pragma unroll
        for (int i = 0; i < 4; i++) {
            la[k][i] += __shfl_down(la[k][i], 32, 64);
            la[k][i] += __shfl_down(la[k][i], 16, 64);
        }
    // RACE FIX: red aliases W2p — all phase-1 W2p reads must complete first.
    __syncthreads();

    // ---- finalize: 2 rounds -> eT8 (bf16, slots {e0..4, 1, 0, 0}) ----
    for (int r = 0; r < 2; r++) {
        if (lane < 16) {
            #pragma unroll
            for (int ii = 0; ii < 2; ii++) {
                int i = 2 * r + ii;
                #pragma unroll
                for (int k = 0; k < K_; k++)
                    red[(ii * 5 + k) * 128 + q * 16 + lane] = la[k][i];
            }
        }
        __syncthreads();
        if (t < 160) {
            int kk0 = t >> 5, rem = t & 31, ii = rem >> 4, m = rem & 15;
            (void)kk0;
            int n = 4 * m + 2 * r + ii;
            if (kk0 == 0) {   // one thread per (ii,m): 32 workers do softmax
                float lg[K_];
                #pragma unroll
                for (int k = 0; k < K_; k++) {
                    float s = b2L[k];
                    #pragma unroll
                    for (int gg = 0; gg < 8; gg++)
                        s += red[(ii * 5 + k) * 128 + gg * 16 + m];
                    lg[k] = s;
                }
                float mx = fmaxf(fmaxf(fmaxf(lg[0], lg[1]), fmaxf(lg[2], lg[3])), lg[4]);
                float e0 = __expf(lg[0] - mx), e1 = __expf(lg[1] - mx),
                      e2 = __expf(lg[2] - mx), e3 = __expf(lg[3] - mx),
                      e4 = __expf(lg[4] - mx);
                float inv = 1.0f / (e0 + e1 + e2 + e3 + e4);
                eT8[n * 4 + 0] = packbf2(e0 * inv, e1 * inv);
                eT8[n * 4 + 1] = packbf2(e2 * inv, e3 * inv);
                eT8[n * 4 + 2] = packbf2(e4 * inv, 1.0f);
                eT8[n * 4 + 3] = 0u;
            }
        }
        __syncthreads();
    }

    // ---- phase 2: output MFMA. D[m=c-sub][n=p] = OVp8 x eT8 (K=32, zero-pad)
    int r16 = lane & 15, gg = lane >> 4;
    const bf16x8 zfrag = *(const bf16x8*)zb;
    size_t base = (size_t)b * C_ * HW_ + (size_t)tile * P_;
    #pragma unroll
    for (int ct = 0; ct < 2; ct++) {
        int ctile = (q * 2 + ct) * 16;
        bf16x8 a = (gg == 0) ? *(const bf16x8*)(OVp8 + (ctile + r16) * 4) : zfrag;
        #pragma unroll
        for (int pt8 = 0; pt8 < 4; pt8++) {
            int ptile = pt8 * 16;
            bf16x8 bb = (gg == 0) ? *(const bf16x8*)(eT8 + (ptile + r16) * 4) : zfrag;
            f32x4 acc = {0.f, 0.f, 0.f, 0.f};
            acc = __builtin_amdgcn_mfma_f32_16x16x32_bf16(a, bb, acc, 0, 0, 0);
            int p = ptile + r16;
            #pragma unroll
            for (int r = 0; r < 4; r++) {
                int c = ctile + 4 * gg + r;
                u32 w = featU[c * PS_ + (p >> 1)];
                float f = (p & 1) ? hi16f(w) : lo16f(w);
                ST<BF>(dout, base + (size_t)c * HW_ + p, f + acc[r]);
            }
        }
    }
    // aux outputs (b==0 slice)
    if (b == 0) {
        const size_t enh = (size_t)B_ * C_ * HW_;
        for (int i = blockIdx.x * 512 + t; i < B_ * K_ * C_; i += NT_ * 512)
            ST<BF>(dout, enh + 1 + i, pt[i]);
        if (blockIdx.x == 0 && t == 0) {
            float s = 0;
            for (int bb2 = 0; bb2 < B_; bb2++) s += divpart[bb2];
            ST<BF>(dout, enh, s / (640.0f + 1e-5f));
        }
    }
}
__global__ __launch_bounds__(512, 6) void k_fin(const void* feat, const void* outb,
                                                const void* gamma, const float* W2,
                                                const float* b2, const float* OV,
                                                const float* pt, const float* divpart,
                                                void* dout) {
    __shared__ __attribute__((aligned(16))) float smem[11788];   // 47,152 B
    __shared__ int cnt;
    int flg = detect_bf(feat, &cnt);
    if (flg) fin_body<true >(feat, outb, gamma, W2, b2, OV, pt, divpart, dout, smem);
    else     fin_body<false>(feat, outb, gamma, W2, b2, OV, pt, divpart, dout, smem);
}

extern "C" void kernel_launch(void* const* d_in, const int* in_sizes, int n_in,
                              void* d_out, int out_size, void* d_ws, size_t ws_size,
                              hipStream_t stream) {
    const void* feat = d_in[0];
    const void* mask = d_in[1];
    const void* pq   = d_in[2];
    const void* temp = d_in[3];
    const void* marg = d_in[4];
    const void* qw   = d_in[5];
    const void* bnw  = d_in[6];
    const void* bnb  = d_in[7];
    const void* bnm  = d_in[8];
    const void* bnv  = d_in[9];
    const void* kw   = d_in[10];
    const void* kb   = d_in[11];
    const void* vw   = d_in[12];
    const void* vb   = d_in[13];
    const void* ow   = d_in[14];
    const void* ob   = d_in[15];
    const void* gm   = d_in[16];

    float* ws  = (float*)d_ws;
    float* ptp = ws;                                    // B*NT*K*C = 2,621,440
    float* mz  = ptp + (size_t)B_ * NT_ * K_ * C_;      // B*NT*K*2 = 20,480
    float* pt  = mz  + (size_t)B_ * NT_ * K_ * 2;       // 40,960
    float* W2  = pt  + B_ * K_ * C_;                    // 40,960
    float* b2  = W2  + B_ * K_ * C_;                    // 160
    float* OV  = b2  + B_ * K_;                         // 40,960
    float* dvp = OV  + B_ * K_ * C_;                    // 32

    hipLaunchKernelGGL(k_simpt, dim3(NT_, B_), dim3(512), 0, stream,
                       feat, mask, temp, pq, ptp, mz);
    hipLaunchKernelGGL(k_mergeprep, dim3(B_ * K_ + B_), dim3(256), 0, stream,
                       feat, qw, kw, kb, vw, vb, ow, bnw, bnb, bnm, bnv, marg,
                       ptp, mz, W2, b2, OV, pt, dvp);
    hipLaunchKernelGGL(k_fin, dim3(NT_, B_), dim3(512), 0, stream,
                       feat, ob, gm, W2, b2, OV, pt, dvp, d_out);
}

// Round 12
// 130.731 us; speedup vs baseline: 1.1724x; 1.1724x over previous
//
#include <hip/hip_runtime.h>
#include <hip/hip_bf16.h>
#include <math.h>

#define B_  32
#define C_  256
#define HW_ 4096
#define K_  5
#define P_  128          // positions per tile
#define NT_ 32           // HW_/P_
#define PS_ 68           // padded LDS row stride (u32 words) for featB/wB (k_simpt)
#define FS_ 66           // featU row stride (u32 words) in k_fin

typedef __hip_bfloat16 bf16;
typedef unsigned int u32;
typedef __attribute__((ext_vector_type(8))) short bf16x8;
typedef __attribute__((ext_vector_type(4))) float f32x4;

// ---------- dtype-flexible load/store ----------
template<bool BF>
__device__ inline float LD(const void* p, size_t i) {
    if (BF) return __bfloat162float(((const bf16*)p)[i]);
    return ((const float*)p)[i];
}
template<bool BF>
__device__ inline void ST(void* p, size_t i, float v) {
    if (BF) ((bf16*)p)[i] = __float2bfloat16(v);
    else    ((float*)p)[i] = v;
}
template<bool BF>
__device__ inline float4 LD4(const void* p, size_t i) {
    if (BF) {
        ushort4 u = *(const ushort4*)((const unsigned short*)p + i);
        float4 r;
        r.x = __uint_as_float(((u32)u.x) << 16);
        r.y = __uint_as_float(((u32)u.y) << 16);
        r.z = __uint_as_float(((u32)u.z) << 16);
        r.w = __uint_as_float(((u32)u.w) << 16);
        return r;
    }
    return *(const float4*)((const float*)p + i);
}
__device__ inline u32 packbf2(float a, float b) {   // a -> low 16
    bf16 x = __float2bfloat16(a), y = __float2bfloat16(b);
    return (((u32)*(unsigned short*)&y) << 16) | (u32)(*(unsigned short*)&x);
}
__device__ inline float lo16f(u32 u) { return __uint_as_float(u << 16); }
__device__ inline float hi16f(u32 u) { return __uint_as_float(u & 0xffff0000u); }

// ---------- in-kernel dtype detect (1 sample/thread, wave-reduced) ----------
// bf16 data: ~100% of samples land in [1e-4, 100]; f32-as-u16: ~54%.
// Threshold at 75% of blockDim — >8 sigma from both populations at >=256 samples.
__device__ int detect_bf(const void* feat, int* cntL) {
    int t = threadIdx.x;
    if (t == 0) *cntL = 0;
    __syncthreads();
    const unsigned short* u = (const unsigned short*)feat;
    float v = __uint_as_float(((u32)u[t]) << 16);
    float a = fabsf(v);
    int local = (a >= 1e-4f && a <= 100.f) ? 1 : 0;
    for (int o = 32; o > 0; o >>= 1) local += __shfl_down(local, o, 64);
    if ((t & 63) == 0) atomicAdd(cntL, local);
    __syncthreads();
    return (*cntL > (int)(3u * blockDim.x / 4u)) ? 1 : 0;
}

// ---------- block reductions (256 threads) ----------
__device__ inline float blk_sum(float v, float* sh) {
    for (int o = 32; o > 0; o >>= 1) v += __shfl_down(v, o, 64);
    int w = threadIdx.x >> 6;
    __syncthreads();
    if ((threadIdx.x & 63) == 0) sh[w] = v;
    __syncthreads();
    return sh[0] + sh[1] + sh[2] + sh[3];
}

// ================= 1: FUSED sim + softmax partial + pt partial (MFMA) ==========
template<bool BF>
__device__ void simpt_body(const void* feat, const void* mask, const void* temp,
                           const void* pq, float* ptp, float* mz, float* smem) {
    u32*   featB = (u32*)smem;                 // [256][PS_] = 17408 u32 (68 KB)
    float* red   = smem + 17408;               // 1536 f32 (finalize rounds)
    u32*   wB    = (u32*)red;                  // alias: [16][PS_], rows 0..4 valid
    float* qL    = smem + 17408 + 1536;        // 1280 f32
    float* simL  = qL;                         // alias after phase 1 (640 used)
    float* sc    = qL + 1280;                  // scalars
    int t = threadIdx.x, lane = t & 63, q = t >> 6;
    int b = blockIdx.y, tile = blockIdx.x;

    if (q < K_) {
        float4 v = LD4<BF>(pq, (size_t)q * C_ + lane * 4);
        float ss = v.x * v.x + v.y * v.y + v.z * v.z + v.w * v.w;
        for (int o = 32; o > 0; o >>= 1) ss += __shfl_xor(ss, o, 64);
        float inv = 1.0f / fmaxf(sqrtf(ss), 1e-12f);
        *(float4*)(qL + q * C_ + lane * 4) =
            make_float4(v.x * inv, v.y * inv, v.z * inv, v.w * inv);
    }
    if (t == 0) sc[0] = 1.0f / fmaxf(LD<BF>(temp, 0), 0.01f);
    __syncthreads();

    int c0 = q * 32, half = lane >> 5, lm = lane & 31;
    float sa[4] = {0.f, 0.f, 0.f, 0.f};
    float da[K_][4];
    #pragma unroll
    for (int k = 0; k < K_; k++)
        #pragma unroll
        for (int i = 0; i < 4; i++) da[k][i] = 0.f;
    size_t gbase = (size_t)b * C_ * HW_ + (size_t)tile * P_ + lm * 4;
    #pragma unroll
    for (int j = 0; j < 16; j++) {
        int c = c0 + 2 * j + half;
        float4 f = LD4<BF>(feat, gbase + (size_t)c * HW_);
        sa[0] += f.x * f.x; sa[1] += f.y * f.y; sa[2] += f.z * f.z; sa[3] += f.w * f.w;
        #pragma unroll
        for (int k = 0; k < K_; k++) {
            float qv = qL[k * C_ + c];
            da[k][0] += f.x * qv; da[k][1] += f.y * qv;
            da[k][2] += f.z * qv; da[k][3] += f.w * qv;
        }
        *(uint2*)&featB[c * PS_ + 2 * lm] =
            make_uint2(packbf2(f.x, f.y), packbf2(f.z, f.w));
    }
    #pragma unroll
    for (int i = 0; i < 4; i++) sa[i] += __shfl_down(sa[i], 32, 64);
    #pragma unroll
    for (int k = 0; k < K_; k++)
        #pragma unroll
        for (int i = 0; i < 4; i++) da[k][i] += __shfl_down(da[k][i], 32, 64);

    // prefetch mask for finalize (removes global load from barrier-locked rounds)
    float4 mpre = make_float4(0.f, 0.f, 0.f, 0.f);
    if (t < 160) mpre = LD4<BF>(mask, (size_t)b * HW_ + tile * P_ + (t & 31) * 4);
    float tinv = sc[0];
    #pragma unroll
    for (int r = 0; r < 4; r++) {
        if (lane < 32) {
            red[0 * 256 + q * 32 + lane] = sa[r];
            #pragma unroll
            for (int k = 0; k < K_; k++) red[(1 + k) * 256 + q * 32 + lane] = da[k][r];
        }
        __syncthreads();
        if (t < 160) {
            int kk = t >> 5, m = t & 31, n = 4 * m + r;
            float ssum = 0.f, dsum = 0.f;
            #pragma unroll
            for (int g = 0; g < 8; g++) {
                ssum += red[0 * 256 + g * 32 + m];
                dsum += red[(1 + kk) * 256 + g * 32 + m];
            }
            float mval = (r == 0) ? mpre.x : (r == 1) ? mpre.y : (r == 2) ? mpre.z : mpre.w;
            simL[kk * P_ + n] = (mval > 0.f)
                ? dsum * (tinv / fmaxf(sqrtf(ssum), 1e-12f)) : -INFINITY;
        }
        __syncthreads();
    }

    if (q < K_) {
        float s0 = simL[q * P_ + 2 * lane], s1 = simL[q * P_ + 2 * lane + 1];
        float m = fmaxf(s0, s1);
        for (int o = 32; o > 0; o >>= 1) m = fmaxf(m, __shfl_xor(m, o, 64));
        float e0 = (s0 == -INFINITY) ? 0.f : __expf(s0 - m);
        float e1 = (s1 == -INFINITY) ? 0.f : __expf(s1 - m);
        float z = e0 + e1;
        for (int o = 32; o > 0; o >>= 1) z += __shfl_xor(z, o, 64);
        wB[q * PS_ + lane] = packbf2(e0, e1);
        if (lane == 0) {
            size_t mzb = ((size_t)(b * NT_ + tile) * K_ + q) * 2;
            mz[mzb] = m; mz[mzb + 1] = z;
        }
    }
    __syncthreads();

    int r16 = lane & 15, g = lane >> 4;
    size_t pb = (size_t)(b * NT_ + tile) * (K_ * C_);
    #pragma unroll
    for (int sub = 0; sub < 2; sub++) {
        int ctile = q * 32 + sub * 16;
        f32x4 acc = {0.f, 0.f, 0.f, 0.f};
        #pragma unroll
        for (int s = 0; s < 4; s++) {
            bf16x8 a = *(const bf16x8*)(featB + (ctile + r16) * PS_ + 16 * s + 4 * g);
            bf16x8 bb = *(const bf16x8*)(wB + r16 * PS_ + 16 * s + 4 * g);
            acc = __builtin_amdgcn_mfma_f32_16x16x32_bf16(a, bb, acc, 0, 0, 0);
        }
        if (r16 < K_) {
            #pragma unroll
            for (int r = 0; r < 4; r++)
                ptp[pb + (size_t)r16 * C_ + ctile + 4 * g + r] = acc[r];
        }
    }
}
__global__ __launch_bounds__(512, 4) void k_simpt(const void* feat, const void* mask,
                                                  const void* temp, const void* pq,
                                                  float* ptp, float* mz) {
    __shared__ __attribute__((aligned(16))) float smem[20232];
    __shared__ int cnt;
    int flg = detect_bf(feat, &cnt);
    if (flg) simpt_body<true >(feat, mask, temp, pq, ptp, mz, smem);
    else     simpt_body<false>(feat, mask, temp, pq, ptp, mz, smem);
}

// ================= 2: merge + prep + div in one kernel =================
__device__ inline float merge_one(const float* ptp, const float* mz,
                                  int b, int kk, int c) {
    float M = -INFINITY;
    #pragma unroll 8
    for (int tl = 0; tl < NT_; tl++)
        M = fmaxf(M, mz[((size_t)(b * NT_ + tl) * K_ + kk) * 2]);
    float Zs = 0.f, acc = 0.f;
    #pragma unroll 8
    for (int tl = 0; tl < NT_; tl++) {
        size_t mzb = ((size_t)(b * NT_ + tl) * K_ + kk) * 2;
        float m_t = mz[mzb], z_t = mz[mzb + 1];
        float s = (m_t == -INFINITY) ? 0.f : __expf(m_t - M);
        Zs += z_t * s;
        acc += ptp[(size_t)(b * NT_ + tl) * (K_ * C_) + kk * C_ + c] * s;
    }
    return (Zs > 0.f) ? acc / Zs : 0.f;
}
template<bool BF>
__device__ void prep_part(const void* qw, const void* kw, const void* kb,
                          const void* vw, const void* vb, const void* ow,
                          const void* bnw, const void* bnb, const void* bnm,
                          const void* bnv, float ptv, int bk,
                          float* W2, float* b2, float* OV, float* pt, float* smem) {
    float* ptL = smem;
    float* KtL = smem + 256;
    float* VtL = smem + 512;
    float* sh  = smem + 768;
    int t = threadIdx.x;
    ptL[t] = ptv;
    pt[(size_t)bk * C_ + t] = ptv;
    __syncthreads();
    float kt = LD<BF>(kb, t), vt = LD<BF>(vb, t);
    for (int c = 0; c < C_; c += 4) {
        float4 p4 = *(float4*)(ptL + c);
        float4 kw4 = LD4<BF>(kw, (size_t)t * C_ + c);
        float4 vw4 = LD4<BF>(vw, (size_t)t * C_ + c);
        kt += kw4.x * p4.x + kw4.y * p4.y + kw4.z * p4.z + kw4.w * p4.w;
        vt += vw4.x * p4.x + vw4.y * p4.y + vw4.z * p4.z + vw4.w * p4.w;
    }
    float scale = LD<BF>(bnw, t) * rsqrtf(LD<BF>(bnv, t) + 1e-5f);
    float shift = LD<BF>(bnb, t) - LD<BF>(bnm, t) * scale;
    KtL[t] = kt * scale;
    VtL[t] = vt;
    float bpart = kt * shift;
    __syncthreads();
    float ov = 0;
    for (int c = 0; c < C_; c += 4) {
        float4 v4 = *(float4*)(VtL + c);
        float4 ow4 = LD4<BF>(ow, (size_t)t * C_ + c);
        ov += ow4.x * v4.x + ow4.y * v4.y + ow4.z * v4.z + ow4.w * v4.w;
    }
    OV[(size_t)bk * C_ + t] = ov;
    float w2 = 0;
    for (int o = 0; o < C_; o++) w2 += KtL[o] * LD<BF>(qw, (size_t)o * C_ + t);
    W2[(size_t)bk * C_ + t] = w2 * (1.0f / 16.0f);
    float bs = blk_sum(bpart, sh);
    if (t == 0) b2[bk] = bs * (1.0f / 16.0f);
}
template<bool BF>
__device__ void div_part(const float* ptp, const float* mz, const void* margin,
                         float* divpart, float* smem) {
    float* ptL = smem;
    float* rn  = smem + K_ * C_;
    float* sh  = rn + 8;
    int b = blockIdx.x - B_ * K_, t = threadIdx.x;
    for (int kk = 0; kk < K_; kk++) ptL[kk * C_ + t] = merge_one(ptp, mz, b, kk, t);
    __syncthreads();
    for (int k = 0; k < K_; k++) {
        float v = ptL[k * C_ + t];
        float s = blk_sum(v * v, sh);
        if (t == 0) rn[k] = 1.0f / fmaxf(sqrtf(s), 1e-12f);
    }
    __syncthreads();
    float m = LD<BF>(margin, 0);
    m = fminf(fmaxf(m, 0.f), 0.5f);
    int p = t >> 3, g = t & 7;
    float contrib = 0.f;
    if (p < K_ * K_) {
        int k = p / K_, j = p % K_;
        float d = 0;
        for (int c = g; c < C_; c += 8) d += ptL[k * C_ + c] * ptL[j * C_ + c];
        d += __shfl_down(d, 4, 8);
        d += __shfl_down(d, 2, 8);
        d += __shfl_down(d, 1, 8);
        if (g == 0 && k != j) contrib = fmaxf(d * rn[k] * rn[j] - m, 0.f);
    }
    float s = blk_sum(contrib, sh);
    if (t == 0) divpart[b] = s;
}
template<bool BF>
__device__ void mergeprep_body(const void* qw, const void* kw, const void* kb,
                               const void* vw, const void* vb, const void* ow,
                               const void* bnw, const void* bnb, const void* bnm,
                               const void* bnv, const void* margin,
                               const float* ptp, const float* mz,
                               float* W2, float* b2, float* OV, float* pt,
                               float* divpart, float* smem) {
    int bid = blockIdx.x, t = threadIdx.x;
    if (bid < B_ * K_) {
        int b = bid / K_, kk = bid % K_;
        float ptv = merge_one(ptp, mz, b, kk, t);
        prep_part<BF>(qw, kw, kb, vw, vb, ow, bnw, bnb, bnm, bnv,
                      ptv, bid, W2, b2, OV, pt, smem);
    } else {
        div_part<BF>(ptp, mz, margin, divpart, smem);
    }
}
__global__ void k_mergeprep(const void* feat, const void* qw, const void* kw,
                            const void* kb, const void* vw, const void* vb,
                            const void* ow, const void* bnw, const void* bnb,
                            const void* bnm, const void* bnv, const void* margin,
                            const float* ptp, const float* mz,
                            float* W2, float* b2, float* OV, float* pt, float* divpart) {
    __shared__ __attribute__((aligned(16))) float smem[K_ * C_ + 16];
    __shared__ int cnt;
    int flg = detect_bf(feat, &cnt);
    if (flg) mergeprep_body<true >(qw, kw, kb, vw, vb, ow, bnw, bnb, bnm, bnv, margin,
                                   ptp, mz, W2, b2, OV, pt, divpart, smem);
    else     mergeprep_body<false>(qw, kw, kb, vw, vb, ow, bnw, bnb, bnm, bnv, margin,
                                   ptp, mz, W2, b2, OV, pt, divpart, smem);
}

// ================= 3: fused refine-attn + residual (output via MFMA) ==========
template<bool BF>
__device__ void fin_body(const void* feat, const void* outb, const void* gamma,
                         const float* W2, const float* b2, const float* OV,
                         const float* pt, const float* divpart,
                         void* dout, float* smem) {
    u32*   featU = (u32*)smem;                  // 16896 u32 (67,584 B)
    u32*   OVp8  = featU + 256 * FS_;           // 1024 u32
    u32*   eT8   = OVp8 + 1024;                 // 512 u32
    u32*   zb    = eT8 + 512;                   // 4 u32 (zero block)
    float* pool  = (float*)(zb + 4);            // 1280 f32: W2p (ph1) / red (finalize)
    u32*   W2p   = (u32*)pool;                  // 640 u32
    float* red   = pool;                        // 1280 f32
    float* b2L   = pool + 1280;                 // 8
    int t = threadIdx.x, lane = t & 63, q = t >> 6;
    int b = blockIdx.y, tile = blockIdx.x;

    float g0 = LD<BF>(gamma, 0);
    for (int i = t; i < 640; i += 512) {
        W2p[i] = packbf2(W2[(size_t)b * 1280 + 2 * i], W2[(size_t)b * 1280 + 2 * i + 1]);
    }
    if (t < 256) {   // OVp8 row c=t: {g*OV[k][c]}k<5, g*ob[c], 0, 0
        float o0 = OV[(size_t)b * 1280 + 0 * C_ + t] * g0;
        float o1 = OV[(size_t)b * 1280 + 1 * C_ + t] * g0;
        float o2 = OV[(size_t)b * 1280 + 2 * C_ + t] * g0;
        float o3 = OV[(size_t)b * 1280 + 3 * C_ + t] * g0;
        float o4 = OV[(size_t)b * 1280 + 4 * C_ + t] * g0;
        float obv = LD<BF>(outb, t) * g0;
        OVp8[t * 4 + 0] = packbf2(o0, o1);
        OVp8[t * 4 + 1] = packbf2(o2, o3);
        OVp8[t * 4 + 2] = packbf2(o4, obv);
        OVp8[t * 4 + 3] = 0u;
    }
    if (t < 4) zb[t] = 0u;
    if (t < K_) b2L[t] = b2[b * K_ + t];
    __syncthreads();

    // ---- phase 1: logit partial dots + plain staging ----
    int c0 = q * 32, half = lane >> 5, lm = lane & 31;
    size_t gbase = (size_t)b * C_ * HW_ + (size_t)tile * P_ + lm * 4;
    float la[K_][4];
    #pragma unroll
    for (int k = 0; k < K_; k++)
        #pragma unroll
        for (int i = 0; i < 4; i++) la[k][i] = 0.f;
    #pragma unroll
    for (int j = 0; j < 16; j++) {
        int c = c0 + 2 * j + half;
        float4 f = LD4<BF>(feat, gbase + (size_t)c * HW_);
        #pragma unroll
        for (int k = 0; k < K_; k++) {
            u32 u = W2p[k * 128 + (c >> 1)];
            float wv = half ? hi16f(u) : lo16f(u);
            la[k][0] += f.x * wv; la[k][1] += f.y * wv;
            la[k][2] += f.z * wv; la[k][3] += f.w * wv;
        }
        *(uint2*)&featU[c * FS_ + 2 * lm] =
            make_uint2(packbf2(f.x, f.y), packbf2(f.z, f.w));
    }
    #pragma unroll
    for (int k = 0; k < K_; k++)
        #pragma unroll
        for (int i = 0; i < 4; i++) la[k][i] += __shfl_down(la[k][i], 32, 64);
    // RACE FIX: red aliases W2p — all phase-1 W2p reads must complete first.
    __syncthreads();

    // ---- finalize rounds -> eT8 (bf16, slots {e0..4, 1, 0, 0}) ----
    #pragma unroll
    for (int r = 0; r < 4; r++) {
        if (lane < 32) {
            #pragma unroll
            for (int k = 0; k < K_; k++) red[k * 256 + q * 32 + lane] = la[k][r];
        }
        __syncthreads();
        if (t < 32) {
            int n = 4 * t + r;
            float lg[K_];
            #pragma unroll
            for (int k = 0; k < K_; k++) {
                float s = b2L[k];
                #pragma unroll
                for (int gg = 0; gg < 8; gg++) s += red[k * 256 + gg * 32 + t];
                lg[k] = s;
            }
            float mx = fmaxf(fmaxf(fmaxf(lg[0], lg[1]), fmaxf(lg[2], lg[3])), lg[4]);
            float e0 = __expf(lg[0] - mx), e1 = __expf(lg[1] - mx),
                  e2 = __expf(lg[2] - mx), e3 = __expf(lg[3] - mx),
                  e4 = __expf(lg[4] - mx);
            float inv = 1.0f / (e0 + e1 + e2 + e3 + e4);
            eT8[n * 4 + 0] = packbf2(e0 * inv, e1 * inv);
            eT8[n * 4 + 1] = packbf2(e2 * inv, e3 * inv);
            eT8[n * 4 + 2] = packbf2(e4 * inv, 1.0f);
            eT8[n * 4 + 3] = 0u;
        }
        __syncthreads();
    }

    // ---- phase 2: output MFMA. D[m=c-sub][n=p] = OVp8 x eT8 (K=32, zero-padded)
    int r16 = lane & 15, gg = lane >> 4;
    const bf16x8 zfrag = *(const bf16x8*)zb;
    size_t base = (size_t)b * C_ * HW_ + (size_t)tile * P_;
    #pragma unroll
    for (int ct = 0; ct < 2; ct++) {
        int ctile = (q * 2 + ct) * 16;
        bf16x8 a = (gg == 0) ? *(const bf16x8*)(OVp8 + (ctile + r16) * 4) : zfrag;
        #pragma unroll
        for (int pt8 = 0; pt8 < 8; pt8++) {
            int ptile = pt8 * 16;
            bf16x8 bb = (gg == 0) ? *(const bf16x8*)(eT8 + (ptile + r16) * 4) : zfrag;
            f32x4 acc = {0.f, 0.f, 0.f, 0.f};
            acc = __builtin_amdgcn_mfma_f32_16x16x32_bf16(a, bb, acc, 0, 0, 0);
            int p = ptile + r16;
            #pragma unroll
            for (int r = 0; r < 4; r++) {
                int c = ctile + 4 * gg + r;
                u32 w = featU[c * FS_ + (p >> 1)];
                float f = (p & 1) ? hi16f(w) : lo16f(w);
                ST<BF>(dout, base + (size_t)c * HW_ + p, f + acc[r]);
            }
        }
    }
    // aux outputs (b==0 slice)
    if (b == 0) {
        const size_t enh = (size_t)B_ * C_ * HW_;
        for (int i = blockIdx.x * 512 + t; i < B_ * K_ * C_; i += NT_ * 512)
            ST<BF>(dout, enh + 1 + i, pt[i]);
        if (blockIdx.x == 0 && t == 0) {
            float s = 0;
            for (int bb2 = 0; bb2 < B_; bb2++) s += divpart[bb2];
            ST<BF>(dout, enh, s / (640.0f + 1e-5f));
        }
    }
}
__global__ __launch_bounds__(512, 4) void k_fin(const void* feat, const void* outb,
                                                const void* gamma, const float* W2,
                                                const float* b2, const float* OV,
                                                const float* pt, const float* divpart,
                                                void* dout) {
    __shared__ __attribute__((aligned(16))) float smem[19728];   // 78,912 B
    __shared__ int cnt;
    int flg = detect_bf(feat, &cnt);
    if (flg) fin_body<true >(feat, outb, gamma, W2, b2, OV, pt, divpart, dout, smem);
    else     fin_body<false>(feat, outb, gamma, W2, b2, OV, pt, divpart, dout, smem);
}

extern "C" void kernel_launch(void* const* d_in, const int* in_sizes, int n_in,
                              void* d_out, int out_size, void* d_ws, size_t ws_size,
                              hipStream_t stream) {
    const void* feat = d_in[0];
    const void* mask = d_in[1];
    const void* pq   = d_in[2];
    const void* temp = d_in[3];
    const void* marg = d_in[4];
    const void* qw   = d_in[5];
    const void* bnw  = d_in[6];
    const void* bnb  = d_in[7];
    const void* bnm  = d_in[8];
    const void* bnv  = d_in[9];
    const void* kw   = d_in[10];
    const void* kb   = d_in[11];
    const void* vw   = d_in[12];
    const void* vb   = d_in[13];
    const void* ow   = d_in[14];
    const void* ob   = d_in[15];
    const void* gm   = d_in[16];

    float* ws  = (float*)d_ws;
    float* ptp = ws;                                    // B*NT*K*C = 1,310,720
    float* mz  = ptp + (size_t)B_ * NT_ * K_ * C_;      // B*NT*K*2 = 10,240
    float* pt  = mz  + (size_t)B_ * NT_ * K_ * 2;       // 40,960
    float* W2  = pt  + B_ * K_ * C_;                    // 40,960
    float* b2  = W2  + B_ * K_ * C_;                    // 160
    float* OV  = b2  + B_ * K_;                         // 40,960
    float* dvp = OV  + B_ * K_ * C_;                    // 32

    hipLaunchKernelGGL(k_simpt, dim3(NT_, B_), dim3(512), 0, stream,
                       feat, mask, temp, pq, ptp, mz);
    hipLaunchKernelGGL(k_mergeprep, dim3(B_ * K_ + B_), dim3(256), 0, stream,
                       feat, qw, kw, kb, vw, vb, ow, bnw, bnb, bnm, bnv, marg,
                       ptp, mz, W2, b2, OV, pt, dvp);
    hipLaunchKernelGGL(k_fin, dim3(NT_, B_), dim3(512), 0, stream,
                       feat, ob, gm, W2, b2, OV, pt, dvp, d_out);
}